// Round 5
// baseline (1518.656 us; speedup 1.0000x reference)
//
#include <hip/hip_runtime.h>
#include <math.h>

#define B_ 32
#define M_ 512
#define N_ 512
#define E_ 768
#define NEG_BIG   -1e12f
#define INV_SCALE 0.03608439182435161f  // 1/sqrt(768)

typedef __attribute__((ext_vector_type(8))) __bf16 bf16x8;
typedef __attribute__((ext_vector_type(4))) float  floatx4;

#define MFMA_BF16 __builtin_amdgcn_mfma_f32_16x16x32_bf16

// Barrier that does NOT drain vmcnt: LDS producer/consumer safety needs only
// lgkmcnt(0)+s_barrier; register-destined global prefetch stays in flight
// across it (T3/T4 mechanism; __syncthreads would emit vmcnt(0) and kill it).
#define BAR() do { asm volatile("s_waitcnt lgkmcnt(0)" ::: "memory"); \
                   __builtin_amdgcn_s_barrier(); } while (0)

// ---------------------------------------------------------------------------
// helpers
// ---------------------------------------------------------------------------
__device__ __forceinline__ void load16(const float* __restrict__ p, float* v) {
    *(float4*)&v[0]  = *(const float4*)(p);
    *(float4*)&v[4]  = *(const float4*)(p + 4);
    *(float4*)&v[8]  = *(const float4*)(p + 8);
    *(float4*)&v[12] = *(const float4*)(p + 12);
}

// split-bf16 convert + swizzled LDS store of 16 f32
__device__ __forceinline__ void cvt_store16(const float* v, __bf16* hi, __bf16* lo,
                                            int row, int h) {
    bf16x8 h0, h1, l0, l1;
#pragma unroll
    for (int j = 0; j < 8; ++j) {
        float x0 = v[j], x1 = v[j + 8];
        __bf16 a0 = (__bf16)x0;
        __bf16 a1 = (__bf16)x1;
        h0[j] = a0;
        h1[j] = a1;
        l0[j] = (__bf16)(x0 - (float)a0);
        l1[j] = (__bf16)(x1 - (float)a1);
    }
    const int xr = (row >> 1) & 3;
    *(bf16x8*)&hi[row * 32 + (((2 * h)     ^ xr) << 3)] = h0;
    *(bf16x8*)&hi[row * 32 + (((2 * h + 1) ^ xr) << 3)] = h1;
    *(bf16x8*)&lo[row * 32 + (((2 * h)     ^ xr) << 3)] = l0;
    *(bf16x8*)&lo[row * 32 + (((2 * h + 1) ^ xr) << 3)] = l1;
}

// pre-split (hi0,hi1,lo0,lo1) -> swizzled LDS store, no cvt
__device__ __forceinline__ void store_pre16(const bf16x8* v, __bf16* hi, __bf16* lo,
                                            int row, int h) {
    const int xr = (row >> 1) & 3;
    *(bf16x8*)&hi[row * 32 + (((2 * h)     ^ xr) << 3)] = v[0];
    *(bf16x8*)&hi[row * 32 + (((2 * h + 1) ^ xr) << 3)] = v[1];
    *(bf16x8*)&lo[row * 32 + (((2 * h)     ^ xr) << 3)] = v[2];
    *(bf16x8*)&lo[row * 32 + (((2 * h + 1) ^ xr) << 3)] = v[3];
}

// one BK=32 step: 16 LDS frag loads + 48 MFMAs (hi*hi + hi*lo + lo*hi)
__device__ __forceinline__ void mfma_step(const __bf16* Ahi, const __bf16* Alo,
                                          const __bf16* Bhi, const __bf16* Blo,
                                          const int (&aoff)[4], const int (&boff)[4],
                                          floatx4 (&acc)[4][4]) {
    bf16x8 bh[4], bl[4];
#pragma unroll
    for (int fn = 0; fn < 4; ++fn) {
        bh[fn] = *(const bf16x8*)&Bhi[boff[fn]];
        bl[fn] = *(const bf16x8*)&Blo[boff[fn]];
    }
#pragma unroll
    for (int fm = 0; fm < 4; ++fm) {
        bf16x8 ah = *(const bf16x8*)&Ahi[aoff[fm]];
        bf16x8 al = *(const bf16x8*)&Alo[aoff[fm]];
#pragma unroll
        for (int fn = 0; fn < 4; ++fn) {
            acc[fm][fn] = MFMA_BF16(ah, bh[fn], acc[fm][fn], 0, 0, 0);
            acc[fm][fn] = MFMA_BF16(ah, bl[fn], acc[fm][fn], 0, 0, 0);
            acc[fm][fn] = MFMA_BF16(al, bh[fn], acc[fm][fn], 0, 0, 0);
        }
    }
}

#define TILE_SETUP()                                                      \
    const int tid = threadIdx.x, lane = tid & 63;                         \
    const int l15 = lane & 15, l4 = lane >> 4;                            \
    const int wid = tid >> 6, wm = wid >> 1, wn = wid & 1;                \
    const int srow = tid >> 1, h = tid & 1;                               \
    int aoff[4], boff[4];                                                 \
    _Pragma("unroll")                                                     \
    for (int f = 0; f < 4; ++f) {                                         \
        int rr = wm * 64 + f * 16 + l15;                                  \
        aoff[f] = rr * 32 + ((l4 ^ ((rr >> 1) & 3)) << 3);                \
        int cc = wn * 64 + f * 16 + l15;                                  \
        boff[f] = cc * 32 + ((l4 ^ ((cc >> 1) & 3)) << 3);                \
    }                                                                     \
    floatx4 acc[4][4];                                                    \
    const floatx4 zero_ = {0.f, 0.f, 0.f, 0.f};                           \
    _Pragma("unroll")                                                     \
    for (int i = 0; i < 4; ++i)                                           \
        _Pragma("unroll")                                                 \
        for (int j = 0; j < 4; ++j) acc[i][j] = zero_;

// ---------------------------------------------------------------------------
// att (NT): att[b,m,n] = mask ? dot(c_hs[m,:], r_hs[n,:])/sqrt(E) : -1e12
// ping-pong reg prefetch: loads for step t+1 in flight during mfma_step(t)
// ---------------------------------------------------------------------------
__global__ __launch_bounds__(256, 2)
void mfma_att(const float* __restrict__ chs, const float* __restrict__ rhs,
              const int* __restrict__ cids, const int* __restrict__ rids,
              float* __restrict__ att) {
    __shared__ __bf16 Ahi[4096], Alo[4096], Bhi[4096], Blo[4096];
    const int b = blockIdx.z, m0 = blockIdx.x * 128, n0 = blockIdx.y * 128;
    TILE_SETUP();
    const float* Ap = chs + ((size_t)b * M_ + m0 + srow) * E_ + h * 16;
    const float* Bp = rhs + ((size_t)b * N_ + n0 + srow) * E_ + h * 16;

    float va[16], vb[16], na[16], nb[16];
    load16(Ap, va); load16(Bp, vb);
#pragma unroll 1
    for (int k0 = 0; k0 < E_; k0 += 64) {
        BAR();
        cvt_store16(va, Ahi, Alo, srow, h);
        cvt_store16(vb, Bhi, Blo, srow, h);
        load16(Ap + k0 + 32, na);
        load16(Bp + k0 + 32, nb);
        BAR();
        mfma_step(Ahi, Alo, Bhi, Blo, aoff, boff, acc);
        BAR();
        cvt_store16(na, Ahi, Alo, srow, h);
        cvt_store16(nb, Bhi, Blo, srow, h);
        if (k0 + 64 < E_) { load16(Ap + k0 + 64, va); load16(Bp + k0 + 64, vb); }
        BAR();
        mfma_step(Ahi, Alo, Bhi, Blo, aoff, boff, acc);
    }

    bool rm[4];
#pragma unroll
    for (int fn = 0; fn < 4; ++fn)
        rm[fn] = rids[b * N_ + n0 + wn * 64 + fn * 16 + l15] != 0;
    float* Cb = att + (size_t)b * M_ * N_;
#pragma unroll
    for (int fm = 0; fm < 4; ++fm) {
        const int rbase = m0 + wm * 64 + fm * 16 + l4 * 4;
#pragma unroll
        for (int r = 0; r < 4; ++r) {
            const int row = rbase + r;
            const bool cm = cids[b * M_ + row] != 0;
#pragma unroll
            for (int fn = 0; fn < 4; ++fn) {
                float vv = (cm && rm[fn]) ? acc[fm][fn][r] * INV_SCALE : NEG_BIG;
                Cb[(size_t)row * N_ + n0 + wn * 64 + fn * 16 + l15] = vv;
            }
        }
    }
}

// ---------------------------------------------------------------------------
// NN (per batch): C = P (512x512, pre-split hi/lo bf16) @ Bg (512x768 f32)
// A: short8 loads (no cvt). B: fp32 LDS bounce transpose + cvt. Prefetched.
// ---------------------------------------------------------------------------
__global__ __launch_bounds__(256, 2)
void mfma_nn(const __bf16* __restrict__ Phi, const __bf16* __restrict__ Plo,
             const float* __restrict__ Bg, float* __restrict__ C) {
    __shared__ __bf16 Ahi[4096], Alo[4096], Bhi[4096], Blo[4096];
    __shared__ float scr[32 * 132];
    const int b = blockIdx.z, m0 = blockIdx.x * 128, n0 = blockIdx.y * 128;
    TILE_SETUP();
    const __bf16* Aph = Phi + ((size_t)b * 512 + m0 + srow) * 512 + h * 16;
    const __bf16* Apl = Plo + ((size_t)b * 512 + m0 + srow) * 512 + h * 16;
    const int kk = tid >> 3, cseg = (tid & 7) * 16;
    const float* Bp = Bg + ((size_t)b * 512 + kk) * E_ + n0 + cseg;

    bf16x8 a0[4], a1[4];
    float w0[16], w1[16];
    a0[0] = *(const bf16x8*)(Aph);     a0[1] = *(const bf16x8*)(Aph + 8);
    a0[2] = *(const bf16x8*)(Apl);     a0[3] = *(const bf16x8*)(Apl + 8);
    load16(Bp, w0);
#pragma unroll 1
    for (int k0 = 0; k0 < 512; k0 += 64) {
        BAR();
        store_pre16(a0, Ahi, Alo, srow, h);
        *(float4*)&scr[kk * 132 + cseg]      = *(float4*)&w0[0];
        *(float4*)&scr[kk * 132 + cseg + 4]  = *(float4*)&w0[4];
        *(float4*)&scr[kk * 132 + cseg + 8]  = *(float4*)&w0[8];
        *(float4*)&scr[kk * 132 + cseg + 12] = *(float4*)&w0[12];
        a1[0] = *(const bf16x8*)(Aph + k0 + 32);
        a1[1] = *(const bf16x8*)(Aph + k0 + 40);
        a1[2] = *(const bf16x8*)(Apl + k0 + 32);
        a1[3] = *(const bf16x8*)(Apl + k0 + 40);
        load16(Bp + (size_t)(k0 + 32) * E_, w1);
        BAR();
        {
            float vb16[16];
#pragma unroll
            for (int j = 0; j < 16; ++j) vb16[j] = scr[(h * 16 + j) * 132 + srow];
            cvt_store16(vb16, Bhi, Blo, srow, h);
        }
        BAR();
        mfma_step(Ahi, Alo, Bhi, Blo, aoff, boff, acc);
        // ---- odd step (k0+32)
        BAR();
        store_pre16(a1, Ahi, Alo, srow, h);
        *(float4*)&scr[kk * 132 + cseg]      = *(float4*)&w1[0];
        *(float4*)&scr[kk * 132 + cseg + 4]  = *(float4*)&w1[4];
        *(float4*)&scr[kk * 132 + cseg + 8]  = *(float4*)&w1[8];
        *(float4*)&scr[kk * 132 + cseg + 12] = *(float4*)&w1[12];
        if (k0 + 64 < 512) {
            a0[0] = *(const bf16x8*)(Aph + k0 + 64);
            a0[1] = *(const bf16x8*)(Aph + k0 + 72);
            a0[2] = *(const bf16x8*)(Apl + k0 + 64);
            a0[3] = *(const bf16x8*)(Apl + k0 + 72);
            load16(Bp + (size_t)(k0 + 64) * E_, w0);
        }
        BAR();
        {
            float vb16[16];
#pragma unroll
            for (int j = 0; j < 16; ++j) vb16[j] = scr[(h * 16 + j) * 132 + srow];
            cvt_store16(vb16, Bhi, Blo, srow, h);
        }
        BAR();
        mfma_step(Ahi, Alo, Bhi, Blo, aoff, boff, acc);
    }

    float* Cb = C + (size_t)b * M_ * E_;
#pragma unroll
    for (int fm = 0; fm < 4; ++fm) {
        const int rbase = m0 + wm * 64 + fm * 16 + l4 * 4;
#pragma unroll
        for (int r = 0; r < 4; ++r)
#pragma unroll
            for (int fn = 0; fn < 4; ++fn)
                Cb[(size_t)(rbase + r) * E_ + n0 + wn * 64 + fn * 16 + l15] =
                    acc[fm][fn][r];
    }
}

// ---------------------------------------------------------------------------
// feature select (seg uniform across block)
// ---------------------------------------------------------------------------
__device__ __forceinline__ void feature16(float* f, const float* a, const float* s,
                                          int seg) {
    if (seg == 0) {
#pragma unroll
        for (int j = 0; j < 16; ++j) f[j] = a[j];
    } else if (seg == 1) {
#pragma unroll
        for (int j = 0; j < 16; ++j) f[j] = s[j];
    } else if (seg == 2) {
#pragma unroll
        for (int j = 0; j < 16; ++j) f[j] = a[j] - s[j];
    } else if (seg == 3) {
#pragma unroll
        for (int j = 0; j < 16; ++j) f[j] = a[j] * s[j];
    } else {
#pragma unroll
        for (int j = 0; j < 16; ++j) { float d = a[j] - s[j]; f[j] = d * d; }
    }
}

// ---------------------------------------------------------------------------
// feat (merged c/r): relu(submult(HAT,HS) @ W_pre + b_pre) with fused masked
// first/sum/max reduction into stats[b][3][768]. W pre-split bf16 (no cvt).
// ---------------------------------------------------------------------------
__global__ __launch_bounds__(256, 2)
void mfma_feat(const float* __restrict__ chat, const float* __restrict__ rhat,
               const float* __restrict__ chs, const float* __restrict__ rhs,
               const __bf16* __restrict__ WThi, const __bf16* __restrict__ WTlo,
               const float* __restrict__ bias, const int* __restrict__ cids,
               const int* __restrict__ rids, float* __restrict__ scs,
               float* __restrict__ srs) {
    __shared__ __bf16 Ahi[4096], Alo[4096], Bhi[4096], Blo[4096];
    const int side = blockIdx.z;
    const float* HAT = side ? rhat : chat;
    const float* HS  = side ? rhs  : chs;
    const int*   ids = side ? rids : cids;
    float*     stats = side ? srs  : scs;
    const int m0 = blockIdx.x * 128, n0 = blockIdx.y * 128;
    TILE_SETUP();
    const float* Hp = HAT + (size_t)(m0 + srow) * E_ + h * 16;
    const float* Sp = HS  + (size_t)(m0 + srow) * E_ + h * 16;
    const __bf16* Wph = WThi + (size_t)(n0 + srow) * 3840 + h * 16;
    const __bf16* Wpl = WTlo + (size_t)(n0 + srow) * 3840 + h * 16;

    float a0v[16], s0v[16], a1v[16], s1v[16];
    bf16x8 w0[4], w1[4];
    load16(Hp, a0v); load16(Sp, s0v);
    w0[0] = *(const bf16x8*)(Wph);     w0[1] = *(const bf16x8*)(Wph + 8);
    w0[2] = *(const bf16x8*)(Wpl);     w0[3] = *(const bf16x8*)(Wpl + 8);

#pragma unroll 1
    for (int t = 0; t < 120; t += 2) {
        {   // even step t
            float f[16];
            feature16(f, a0v, s0v, t / 24);
            BAR();
            cvt_store16(f, Ahi, Alo, srow, h);
            store_pre16(w0, Bhi, Blo, srow, h);
            const int t1 = t + 1;                    // always < 120
            const int e1 = (t1 % 24) * 32;
            load16(Hp + e1, a1v); load16(Sp + e1, s1v);
            w1[0] = *(const bf16x8*)(Wph + t1 * 32);
            w1[1] = *(const bf16x8*)(Wph + t1 * 32 + 8);
            w1[2] = *(const bf16x8*)(Wpl + t1 * 32);
            w1[3] = *(const bf16x8*)(Wpl + t1 * 32 + 8);
            BAR();
            mfma_step(Ahi, Alo, Bhi, Blo, aoff, boff, acc);
        }
        {   // odd step t+1
            float f[16];
            feature16(f, a1v, s1v, (t + 1) / 24);
            BAR();
            cvt_store16(f, Ahi, Alo, srow, h);
            store_pre16(w1, Bhi, Blo, srow, h);
            if (t + 2 < 120) {
                const int t2 = t + 2;
                const int e2 = (t2 % 24) * 32;
                load16(Hp + e2, a0v); load16(Sp + e2, s0v);
                w0[0] = *(const bf16x8*)(Wph + t2 * 32);
                w0[1] = *(const bf16x8*)(Wph + t2 * 32 + 8);
                w0[2] = *(const bf16x8*)(Wpl + t2 * 32);
                w0[3] = *(const bf16x8*)(Wpl + t2 * 32 + 8);
            }
            BAR();
            mfma_step(Ahi, Alo, Bhi, Blo, aoff, boff, acc);
        }
    }

    const int b = m0 >> 9;
    float bv[4];
#pragma unroll
    for (int fn = 0; fn < 4; ++fn)
        bv[fn] = bias[n0 + wn * 64 + fn * 16 + l15];
    float sum4[4] = {0.f, 0.f, 0.f, 0.f}, max4[4] = {0.f, 0.f, 0.f, 0.f};
#pragma unroll
    for (int fm = 0; fm < 4; ++fm) {
        const int rbase = m0 + wm * 64 + fm * 16 + l4 * 4;
#pragma unroll
        for (int r = 0; r < 4; ++r) {
            const int g = rbase + r;
            const bool valid = ids[g] != 0;
#pragma unroll
            for (int fn = 0; fn < 4; ++fn) {
                float v = fmaxf(acc[fm][fn][r] + bv[fn], 0.f);
                v = valid ? v : 0.f;
                sum4[fn] += v;
                max4[fn] = fmaxf(max4[fn], v);
                if ((g & 511) == 0)   // row 0 of this batch -> "first" stat
                    stats[b * 2304 + n0 + wn * 64 + fn * 16 + l15] = v;
            }
        }
    }
#pragma unroll
    for (int fn = 0; fn < 4; ++fn) {
        float s = sum4[fn];
        s += __shfl_xor(s, 16); s += __shfl_xor(s, 32);
        float mx = max4[fn];
        mx = fmaxf(mx, __shfl_xor(mx, 16)); mx = fmaxf(mx, __shfl_xor(mx, 32));
        if (l4 == 0) {
            const int col = n0 + wn * 64 + fn * 16 + l15;
            atomicAdd(&stats[b * 2304 + 768 + col], s);
            atomicMax((int*)&stats[b * 2304 + 1536 + col], __float_as_int(mx));
        }
    }
}

// ---------------------------------------------------------------------------
// W_pre [3840][768] f32 -> WThi/WTlo [768][3840] bf16 (transpose + split)
// ---------------------------------------------------------------------------
__global__ __launch_bounds__(256)
void split_w(const float* __restrict__ src, __bf16* __restrict__ whi,
             __bf16* __restrict__ wlo) {
    __shared__ float tile[32][33];
    const int c0 = blockIdx.x * 32;   // n
    const int r0 = blockIdx.y * 32;   // k
    const int tx = threadIdx.x & 31, ty = threadIdx.x >> 5;
#pragma unroll
    for (int i = 0; i < 32; i += 8)
        tile[ty + i][tx] = src[(size_t)(r0 + ty + i) * 768 + c0 + tx];
    __syncthreads();
    const int nr = threadIdx.x >> 3, kq = (threadIdx.x & 7) * 4;
#pragma unroll
    for (int j = 0; j < 4; ++j) {
        float v = tile[kq + j][nr];
        __bf16 hv = (__bf16)v;
        whi[(size_t)(c0 + nr) * 3840 + r0 + kq + j] = hv;
        wlo[(size_t)(c0 + nr) * 3840 + r0 + kq + j] = (__bf16)(v - (float)hv);
    }
}

// ---------------------------------------------------------------------------
// Row softmax, emitting pre-split hi/lo bf16
// ---------------------------------------------------------------------------
__global__ __launch_bounds__(256)
void softmax_rows(const float* __restrict__ att, __bf16* __restrict__ phi,
                  __bf16* __restrict__ plo) {
    const int wave = threadIdx.x >> 6;
    const int lane = threadIdx.x & 63;
    const size_t row = (size_t)blockIdx.x * 4 + wave;
    const float* x = att + row * N_;
    float v[8];
    float mx = -INFINITY;
#pragma unroll
    for (int i = 0; i < 8; ++i) { v[i] = x[lane + i * 64]; mx = fmaxf(mx, v[i]); }
#pragma unroll
    for (int off = 32; off; off >>= 1) mx = fmaxf(mx, __shfl_xor(mx, off));
    float s = 0.f;
#pragma unroll
    for (int i = 0; i < 8; ++i) { v[i] = __expf(v[i] - mx); s += v[i]; }
#pragma unroll
    for (int off = 32; off; off >>= 1) s += __shfl_xor(s, off);
    const float inv = 1.f / s;
#pragma unroll
    for (int i = 0; i < 8; ++i) {
        float val = v[i] * inv;
        __bf16 hv = (__bf16)val;
        phi[row * N_ + lane + i * 64] = hv;
        plo[row * N_ + lane + i * 64] = (__bf16)(val - (float)hv);
    }
}

// ---------------------------------------------------------------------------
// Column softmax (over m), transposed pre-split output P2t[b,n,m] hi/lo
// ---------------------------------------------------------------------------
__global__ __launch_bounds__(256)
void softmax_cols_t(const float* __restrict__ att, __bf16* __restrict__ dhi,
                    __bf16* __restrict__ dlo) {
    __shared__ float tile[512][17];
    __shared__ float red[16][16];
    __shared__ float invs[16];
    const int b = blockIdx.x, n0 = blockIdx.y * 16;
    const int tid = threadIdx.x;
    const int c = tid & 15, r = tid >> 4;
    const float* src = att + (size_t)b * M_ * N_ + n0;
#pragma unroll 4
    for (int i = 0; i < 32; ++i) {
        int m = r + i * 16;
        tile[m][c] = src[(size_t)m * N_ + c];
    }
    __syncthreads();
    float mx = -INFINITY;
    for (int m = r; m < 512; m += 16) mx = fmaxf(mx, tile[m][c]);
    red[r][c] = mx;
    __syncthreads();
    if (r == 0) {
        float m2 = red[0][c];
#pragma unroll
        for (int j = 1; j < 16; ++j) m2 = fmaxf(m2, red[j][c]);
        invs[c] = m2;
    }
    __syncthreads();
    const float cmx = invs[c];
    float s = 0.f;
    for (int m = r; m < 512; m += 16) {
        float e = __expf(tile[m][c] - cmx);
        tile[m][c] = e;
        s += e;
    }
    __syncthreads();
    red[r][c] = s;
    __syncthreads();
    if (r == 0) {
        float st = 0.f;
#pragma unroll
        for (int j = 0; j < 16; ++j) st += red[j][c];
        invs[c] = 1.f / st;
    }
    __syncthreads();
#pragma unroll 4
    for (int i = 0; i < 32; ++i) {
        int lin = tid + i * 256;
        int cc = lin >> 9;
        int m = lin & 511;
        float val = tile[m][cc] * invs[cc];
        __bf16 hv = (__bf16)val;
        const size_t o = ((size_t)b * N_ + n0 + cc) * M_ + m;
        dhi[o] = hv;
        dlo[o] = (__bf16)(val - (float)hv);
    }
}

// ---------------------------------------------------------------------------
// stats -> m_vs[b][11520] (submult of [first, sum/cnt, max] features)
// ---------------------------------------------------------------------------
__global__ __launch_bounds__(256)
void ffprep_kernel(const float* __restrict__ sc, const float* __restrict__ sr,
                   const int* __restrict__ cids, const int* __restrict__ rids,
                   float* __restrict__ mv) {
    __shared__ int redc[4], redr[4];
    const int b = blockIdx.x, tid = threadIdx.x;
    int cc = 0, cr = 0;
    for (int m = tid; m < 512; m += 256) {
        cc += (cids[b * 512 + m] != 0);
        cr += (rids[b * 512 + m] != 0);
    }
#pragma unroll
    for (int off = 32; off; off >>= 1) {
        cc += __shfl_xor(cc, off);
        cr += __shfl_xor(cr, off);
    }
    if ((tid & 63) == 0) { redc[tid >> 6] = cc; redr[tid >> 6] = cr; }
    __syncthreads();
    const float invc = 1.f / (float)(redc[0] + redc[1] + redc[2] + redc[3]);
    const float invr = 1.f / (float)(redr[0] + redr[1] + redr[2] + redr[3]);
    const float* scb = sc + b * 2304;
    const float* srb = sr + b * 2304;
    float* mvb = mv + (size_t)b * 11520;
    for (int i = tid; i < 2304; i += 256) {
        float a = scb[i], r = srb[i];
        if (i >= 768 && i < 1536) { a *= invc; r *= invr; }
        float d = a - r;
        mvb[i]        = a;
        mvb[2304 + i] = r;
        mvb[4608 + i] = d;
        mvb[6912 + i] = a * r;
        mvb[9216 + i] = d * d;
    }
}

// ---------------------------------------------------------------------------
// hacc[b][j] += partial dot over e-chunk; each W_ff1 element read once.
// ---------------------------------------------------------------------------
__global__ __launch_bounds__(256)
void ff1_kernel(const float* __restrict__ mv, const float* __restrict__ W1,
                float* __restrict__ hacc) {
    const int j = blockIdx.x * 256 + threadIdx.x;
    const int e0 = blockIdx.y * 720;
    float acc[32];
#pragma unroll
    for (int b = 0; b < 32; ++b) acc[b] = 0.f;
    for (int ec = 0; ec < 720; ec += 4) {
        const float w0 = W1[(size_t)(e0 + ec + 0) * 768 + j];
        const float w1 = W1[(size_t)(e0 + ec + 1) * 768 + j];
        const float w2 = W1[(size_t)(e0 + ec + 2) * 768 + j];
        const float w3 = W1[(size_t)(e0 + ec + 3) * 768 + j];
#pragma unroll
        for (int b = 0; b < 32; ++b) {
            const float* mp = mv + (size_t)b * 11520 + e0 + ec;
            float a = acc[b];
            a = fmaf(mp[0], w0, a);
            a = fmaf(mp[1], w1, a);
            a = fmaf(mp[2], w2, a);
            a = fmaf(mp[3], w3, a);
            acc[b] = a;
        }
    }
#pragma unroll
    for (int b = 0; b < 32; ++b) atomicAdd(&hacc[b * 768 + j], acc[b]);
}

// ---------------------------------------------------------------------------
// scores[b] = b2 + sum_j relu(hacc + b1)[j] * W2[j]
// ---------------------------------------------------------------------------
__global__ __launch_bounds__(256)
void score_kernel(const float* __restrict__ hacc, const float* __restrict__ b1,
                  const float* __restrict__ W2, const float* __restrict__ b2,
                  float* __restrict__ out) {
    const int b = blockIdx.x, tid = threadIdx.x;
    float acc = 0.f;
    for (int j = tid; j < 768; j += 256)
        acc += fmaxf(hacc[b * 768 + j] + b1[j], 0.f) * W2[j];
#pragma unroll
    for (int off = 32; off; off >>= 1) acc += __shfl_xor(acc, off);
    __shared__ float red[4];
    if ((tid & 63) == 0) red[tid >> 6] = acc;
    __syncthreads();
    if (tid == 0) out[b] = red[0] + red[1] + red[2] + red[3] + b2[0];
}

// ---------------------------------------------------------------------------
extern "C" void kernel_launch(void* const* d_in, const int* in_sizes, int n_in,
                              void* d_out, int out_size, void* d_ws, size_t ws_size,
                              hipStream_t stream) {
    const int*   c_ids = (const int*)d_in[0];
    const int*   r_ids = (const int*)d_in[1];
    const float* c_hs  = (const float*)d_in[2];
    const float* r_hs  = (const float*)d_in[3];
    const float* W_pre = (const float*)d_in[4];
    const float* b_pre = (const float*)d_in[5];
    const float* W_ff1 = (const float*)d_in[6];
    const float* b_ff1 = (const float*)d_in[7];
    const float* W_ff2 = (const float*)d_in[8];
    const float* b_ff2 = (const float*)d_in[9];
    float* out = (float*)d_out;
    float* ws  = (float*)d_ws;

    // Aliased layout (float offsets). Peak 37,748,736 floats = 144.0 MiB
    // (same footprint as the R4 run):
    //   att    [0,        8388608)   dead after softmaxes
    //   P1hi   [8388608, 12582912)   bf16 pair; dead after nn-chat
    //   P1lo   [12582912,16777216)
    //   P2thi  [16777216,20971520)   bf16 pair; dead after nn-rhat
    //   P2tlo  [20971520,25165824)
    //   chat   [25165824,37748736)   live through feat
    //   rhat   [0,       12582912)   over dead att+P1hi (written by nn-rhat)
    //   WThi/WTlo + sc/sr/hacc/mv inside dead-P1lo [12582912,16777216)
    float* att   = ws;
    __bf16* P1hi  = (__bf16*)(ws + 8388608);
    __bf16* P1lo  = (__bf16*)(ws + 12582912);
    __bf16* P2thi = (__bf16*)(ws + 16777216);
    __bf16* P2tlo = (__bf16*)(ws + 20971520);
    float* chat  = ws + 25165824;
    float* rhat  = ws;
    __bf16* WThi  = (__bf16*)(ws + 12582912);   // 2,949,120 bf16 = 1,474,560 f
    __bf16* WTlo  = (__bf16*)(ws + 14057472);
    float* sc    = ws + 15532032;               // [B][3][768]
    float* sr    = sc + 73728;
    float* hacc  = sr + 73728;
    float* mv    = hacc + 24576;                // ends 16,072,704 < 16,777,216

    // 1. attention logits (masked, scaled)
    mfma_att<<<dim3(4, 4, 32), 256, 0, stream>>>(c_hs, r_hs, c_ids, r_ids, att);
    // 2. softmaxes -> pre-split bf16 pairs
    softmax_rows  <<<dim3(B_ * M_ / 4), 256, 0, stream>>>(att, P1hi, P1lo);
    softmax_cols_t<<<dim3(B_, 32), 256, 0, stream>>>(att, P2thi, P2tlo);
    // 3a. c_hat = P1 @ r_hs   (P1 dead after)
    mfma_nn<<<dim3(4, 6, 32), 256, 0, stream>>>(P1hi, P1lo, r_hs, chat);
    // P1 region free: W transpose+split, zero stats
    split_w<<<dim3(24, 120), 256, 0, stream>>>(W_pre, WThi, WTlo);
    hipMemsetAsync(sc, 0, 172032 * sizeof(float), stream);
    // 3b. r_hat = P2t @ c_hs  (P2t dead after)
    mfma_nn<<<dim3(4, 6, 32), 256, 0, stream>>>(P2thi, P2tlo, c_hs, rhat);
    // 4. merged fused feature GEMM + masked first/sum/max reductions
    mfma_feat<<<dim3(128, 6, 2), 256, 0, stream>>>(chat, rhat, c_hs, r_hs,
                                                   WThi, WTlo, b_pre,
                                                   c_ids, r_ids, sc, sr);
    // 5. FF head
    ffprep_kernel<<<dim3(32), 256, 0, stream>>>(sc, sr, c_ids, r_ids, mv);
    ff1_kernel<<<dim3(3, 16), 256, 0, stream>>>(mv, W_ff1, hacc);
    score_kernel<<<dim3(32), 256, 0, stream>>>(hacc, b_ff1, W_ff2, b_ff2, out);
}

// Round 6
// 1443.384 us; speedup vs baseline: 1.0522x; 1.0522x over previous
//
#include <hip/hip_runtime.h>
#include <math.h>

#define B_ 32
#define M_ 512
#define N_ 512
#define E_ 768
#define NEG_BIG   -1e12f
#define INV_SCALE 0.03608439182435161f  // 1/sqrt(768)

typedef __attribute__((ext_vector_type(8))) __bf16 bf16x8;
typedef __attribute__((ext_vector_type(4))) float  floatx4;

#define MFMA_BF16 __builtin_amdgcn_mfma_f32_16x16x32_bf16

// Barrier that does NOT drain vmcnt: LDS producer/consumer safety needs only
// lgkmcnt(0)+s_barrier; register-destined global prefetch stays in flight
// across it (T3/T4 mechanism; __syncthreads would emit vmcnt(0) and kill it).
#define BAR() do { asm volatile("s_waitcnt lgkmcnt(0)" ::: "memory"); \
                   __builtin_amdgcn_s_barrier(); } while (0)

// ---------------------------------------------------------------------------
// helpers
// ---------------------------------------------------------------------------
__device__ __forceinline__ void load16(const float* __restrict__ p, float* v) {
    *(float4*)&v[0]  = *(const float4*)(p);
    *(float4*)&v[4]  = *(const float4*)(p + 4);
    *(float4*)&v[8]  = *(const float4*)(p + 8);
    *(float4*)&v[12] = *(const float4*)(p + 12);
}

// split-bf16 convert + swizzled LDS store of 16 f32
__device__ __forceinline__ void cvt_store16(const float* v, __bf16* hi, __bf16* lo,
                                            int row, int h) {
    bf16x8 h0, h1, l0, l1;
#pragma unroll
    for (int j = 0; j < 8; ++j) {
        float x0 = v[j], x1 = v[j + 8];
        __bf16 a0 = (__bf16)x0;
        __bf16 a1 = (__bf16)x1;
        h0[j] = a0;
        h1[j] = a1;
        l0[j] = (__bf16)(x0 - (float)a0);
        l1[j] = (__bf16)(x1 - (float)a1);
    }
    const int xr = (row >> 1) & 3;
    *(bf16x8*)&hi[row * 32 + (((2 * h)     ^ xr) << 3)] = h0;
    *(bf16x8*)&hi[row * 32 + (((2 * h + 1) ^ xr) << 3)] = h1;
    *(bf16x8*)&lo[row * 32 + (((2 * h)     ^ xr) << 3)] = l0;
    *(bf16x8*)&lo[row * 32 + (((2 * h + 1) ^ xr) << 3)] = l1;
}

// pre-split (hi0,hi1,lo0,lo1) -> swizzled LDS store, no cvt
__device__ __forceinline__ void store_pre16(const bf16x8* v, __bf16* hi, __bf16* lo,
                                            int row, int h) {
    const int xr = (row >> 1) & 3;
    *(bf16x8*)&hi[row * 32 + (((2 * h)     ^ xr) << 3)] = v[0];
    *(bf16x8*)&hi[row * 32 + (((2 * h + 1) ^ xr) << 3)] = v[1];
    *(bf16x8*)&lo[row * 32 + (((2 * h)     ^ xr) << 3)] = v[2];
    *(bf16x8*)&lo[row * 32 + (((2 * h + 1) ^ xr) << 3)] = v[3];
}

// one BK=32 step: 16 LDS frag loads + 48 MFMAs (hi*hi + hi*lo + lo*hi)
__device__ __forceinline__ void mfma_step(const __bf16* Ahi, const __bf16* Alo,
                                          const __bf16* Bhi, const __bf16* Blo,
                                          const int (&aoff)[4], const int (&boff)[4],
                                          floatx4 (&acc)[4][4]) {
    bf16x8 bh[4], bl[4];
#pragma unroll
    for (int fn = 0; fn < 4; ++fn) {
        bh[fn] = *(const bf16x8*)&Bhi[boff[fn]];
        bl[fn] = *(const bf16x8*)&Blo[boff[fn]];
    }
#pragma unroll
    for (int fm = 0; fm < 4; ++fm) {
        bf16x8 ah = *(const bf16x8*)&Ahi[aoff[fm]];
        bf16x8 al = *(const bf16x8*)&Alo[aoff[fm]];
#pragma unroll
        for (int fn = 0; fn < 4; ++fn) {
            acc[fm][fn] = MFMA_BF16(ah, bh[fn], acc[fm][fn], 0, 0, 0);
            acc[fm][fn] = MFMA_BF16(ah, bl[fn], acc[fm][fn], 0, 0, 0);
            acc[fm][fn] = MFMA_BF16(al, bh[fn], acc[fm][fn], 0, 0, 0);
        }
    }
}

#define TILE_SETUP()                                                      \
    const int tid = threadIdx.x, lane = tid & 63;                         \
    const int l15 = lane & 15, l4 = lane >> 4;                            \
    const int wid = tid >> 6, wm = wid >> 1, wn = wid & 1;                \
    const int srow = tid >> 1, h = tid & 1;                               \
    int aoff[4], boff[4];                                                 \
    _Pragma("unroll")                                                     \
    for (int f = 0; f < 4; ++f) {                                         \
        int rr = wm * 64 + f * 16 + l15;                                  \
        aoff[f] = rr * 32 + ((l4 ^ ((rr >> 1) & 3)) << 3);                \
        int cc = wn * 64 + f * 16 + l15;                                  \
        boff[f] = cc * 32 + ((l4 ^ ((cc >> 1) & 3)) << 3);                \
    }                                                                     \
    floatx4 acc[4][4];                                                    \
    const floatx4 zero_ = {0.f, 0.f, 0.f, 0.f};                           \
    _Pragma("unroll")                                                     \
    for (int i = 0; i < 4; ++i)                                           \
        _Pragma("unroll")                                                 \
        for (int j = 0; j < 4; ++j) acc[i][j] = zero_;

// ---------------------------------------------------------------------------
// att (NT): att[b,m,n] = mask ? dot(c_hs[m,:], r_hs[n,:])/sqrt(E) : -1e12
// ping-pong reg prefetch: loads for step t+1 in flight during mfma_step(t)
// ---------------------------------------------------------------------------
__global__ __launch_bounds__(256, 2)
void mfma_att(const float* __restrict__ chs, const float* __restrict__ rhs,
              const int* __restrict__ cids, const int* __restrict__ rids,
              float* __restrict__ att) {
    __shared__ __bf16 Ahi[4096], Alo[4096], Bhi[4096], Blo[4096];
    const int b = blockIdx.z, m0 = blockIdx.x * 128, n0 = blockIdx.y * 128;
    TILE_SETUP();
    const float* Ap = chs + ((size_t)b * M_ + m0 + srow) * E_ + h * 16;
    const float* Bp = rhs + ((size_t)b * N_ + n0 + srow) * E_ + h * 16;

    float va[16], vb[16], na[16], nb[16];
    load16(Ap, va); load16(Bp, vb);
#pragma unroll 1
    for (int k0 = 0; k0 < E_; k0 += 64) {
        BAR();
        cvt_store16(va, Ahi, Alo, srow, h);
        cvt_store16(vb, Bhi, Blo, srow, h);
        load16(Ap + k0 + 32, na);
        load16(Bp + k0 + 32, nb);
        BAR();
        mfma_step(Ahi, Alo, Bhi, Blo, aoff, boff, acc);
        BAR();
        cvt_store16(na, Ahi, Alo, srow, h);
        cvt_store16(nb, Bhi, Blo, srow, h);
        if (k0 + 64 < E_) { load16(Ap + k0 + 64, va); load16(Bp + k0 + 64, vb); }
        BAR();
        mfma_step(Ahi, Alo, Bhi, Blo, aoff, boff, acc);
    }

    bool rm[4];
#pragma unroll
    for (int fn = 0; fn < 4; ++fn)
        rm[fn] = rids[b * N_ + n0 + wn * 64 + fn * 16 + l15] != 0;
    float* Cb = att + (size_t)b * M_ * N_;
#pragma unroll
    for (int fm = 0; fm < 4; ++fm) {
        const int rbase = m0 + wm * 64 + fm * 16 + l4 * 4;
#pragma unroll
        for (int r = 0; r < 4; ++r) {
            const int row = rbase + r;
            const bool cm = cids[b * M_ + row] != 0;
#pragma unroll
            for (int fn = 0; fn < 4; ++fn) {
                float vv = (cm && rm[fn]) ? acc[fm][fn][r] * INV_SCALE : NEG_BIG;
                Cb[(size_t)row * N_ + n0 + wn * 64 + fn * 16 + l15] = vv;
            }
        }
    }
}

// ---------------------------------------------------------------------------
// NN (per batch): C = P (512x512, pre-split hi/lo bf16) @ Bg (512x768 f32)
// A: bf16x8 loads (no cvt). B: fp32 LDS bounce transpose + cvt. Prefetched.
// ---------------------------------------------------------------------------
__global__ __launch_bounds__(256, 2)
void mfma_nn(const __bf16* __restrict__ Phi, const __bf16* __restrict__ Plo,
             const float* __restrict__ Bg, float* __restrict__ C) {
    __shared__ __bf16 Ahi[4096], Alo[4096], Bhi[4096], Blo[4096];
    __shared__ float scr[32 * 132];
    const int b = blockIdx.z, m0 = blockIdx.x * 128, n0 = blockIdx.y * 128;
    TILE_SETUP();
    const __bf16* Aph = Phi + ((size_t)b * 512 + m0 + srow) * 512 + h * 16;
    const __bf16* Apl = Plo + ((size_t)b * 512 + m0 + srow) * 512 + h * 16;
    const int kk = tid >> 3, cseg = (tid & 7) * 16;
    const float* Bp = Bg + ((size_t)b * 512 + kk) * E_ + n0 + cseg;

    bf16x8 a0[4], a1[4];
    float w0[16], w1[16];
    a0[0] = *(const bf16x8*)(Aph);     a0[1] = *(const bf16x8*)(Aph + 8);
    a0[2] = *(const bf16x8*)(Apl);     a0[3] = *(const bf16x8*)(Apl + 8);
    load16(Bp, w0);
#pragma unroll 1
    for (int k0 = 0; k0 < 512; k0 += 64) {
        BAR();
        store_pre16(a0, Ahi, Alo, srow, h);
        *(float4*)&scr[kk * 132 + cseg]      = *(float4*)&w0[0];
        *(float4*)&scr[kk * 132 + cseg + 4]  = *(float4*)&w0[4];
        *(float4*)&scr[kk * 132 + cseg + 8]  = *(float4*)&w0[8];
        *(float4*)&scr[kk * 132 + cseg + 12] = *(float4*)&w0[12];
        a1[0] = *(const bf16x8*)(Aph + k0 + 32);
        a1[1] = *(const bf16x8*)(Aph + k0 + 40);
        a1[2] = *(const bf16x8*)(Apl + k0 + 32);
        a1[3] = *(const bf16x8*)(Apl + k0 + 40);
        load16(Bp + (size_t)(k0 + 32) * E_, w1);
        BAR();
        {
            float vb16[16];
#pragma unroll
            for (int j = 0; j < 16; ++j) vb16[j] = scr[(h * 16 + j) * 132 + srow];
            cvt_store16(vb16, Bhi, Blo, srow, h);
        }
        BAR();
        mfma_step(Ahi, Alo, Bhi, Blo, aoff, boff, acc);
        // ---- odd step (k0+32)
        BAR();
        store_pre16(a1, Ahi, Alo, srow, h);
        *(float4*)&scr[kk * 132 + cseg]      = *(float4*)&w1[0];
        *(float4*)&scr[kk * 132 + cseg + 4]  = *(float4*)&w1[4];
        *(float4*)&scr[kk * 132 + cseg + 8]  = *(float4*)&w1[8];
        *(float4*)&scr[kk * 132 + cseg + 12] = *(float4*)&w1[12];
        if (k0 + 64 < 512) {
            a0[0] = *(const bf16x8*)(Aph + k0 + 64);
            a0[1] = *(const bf16x8*)(Aph + k0 + 72);
            a0[2] = *(const bf16x8*)(Apl + k0 + 64);
            a0[3] = *(const bf16x8*)(Apl + k0 + 72);
            load16(Bp + (size_t)(k0 + 64) * E_, w0);
        }
        BAR();
        {
            float vb16[16];
#pragma unroll
            for (int j = 0; j < 16; ++j) vb16[j] = scr[(h * 16 + j) * 132 + srow];
            cvt_store16(vb16, Bhi, Blo, srow, h);
        }
        BAR();
        mfma_step(Ahi, Alo, Bhi, Blo, aoff, boff, acc);
    }

    float* Cb = C + (size_t)b * M_ * E_;
#pragma unroll
    for (int fm = 0; fm < 4; ++fm) {
        const int rbase = m0 + wm * 64 + fm * 16 + l4 * 4;
#pragma unroll
        for (int r = 0; r < 4; ++r)
#pragma unroll
            for (int fn = 0; fn < 4; ++fn)
                Cb[(size_t)(rbase + r) * E_ + n0 + wn * 64 + fn * 16 + l15] =
                    acc[fm][fn][r];
    }
}

// ---------------------------------------------------------------------------
// feature select, 4 folded segments: 0:a  1:b  2:a*b  3:(a-b)^2
// (the linear a-b segment is folded into W: a@(W0+W2) + b@(W1-W2))
// ---------------------------------------------------------------------------
__device__ __forceinline__ void feature16(float* f, const float* a, const float* s,
                                          int seg) {
    if (seg == 0) {
#pragma unroll
        for (int j = 0; j < 16; ++j) f[j] = a[j];
    } else if (seg == 1) {
#pragma unroll
        for (int j = 0; j < 16; ++j) f[j] = s[j];
    } else if (seg == 2) {
#pragma unroll
        for (int j = 0; j < 16; ++j) f[j] = a[j] * s[j];
    } else {
#pragma unroll
        for (int j = 0; j < 16; ++j) { float d = a[j] - s[j]; f[j] = d * d; }
    }
}

// ---------------------------------------------------------------------------
// feat: relu(submult(HAT,HS) @ W_pre + b_pre) with fused masked first/sum/max
// reduction into stats[b][3][768]. Folded K=3072, W pre-split bf16 (no cvt).
// ---------------------------------------------------------------------------
__global__ __launch_bounds__(256, 2)
void mfma_feat(const float* __restrict__ HAT, const float* __restrict__ HS,
               const __bf16* __restrict__ WThi, const __bf16* __restrict__ WTlo,
               const float* __restrict__ bias, const int* __restrict__ ids,
               float* __restrict__ stats) {
    __shared__ __bf16 Ahi[4096], Alo[4096], Bhi[4096], Blo[4096];
    const int m0 = blockIdx.x * 128, n0 = blockIdx.y * 128;
    TILE_SETUP();
    const float* Hp = HAT + (size_t)(m0 + srow) * E_ + h * 16;
    const float* Sp = HS  + (size_t)(m0 + srow) * E_ + h * 16;
    const __bf16* Wph = WThi + (size_t)(n0 + srow) * 3072 + h * 16;
    const __bf16* Wpl = WTlo + (size_t)(n0 + srow) * 3072 + h * 16;

    float a0v[16], s0v[16], a1v[16], s1v[16];
    bf16x8 w0[4], w1[4];
    load16(Hp, a0v); load16(Sp, s0v);
    w0[0] = *(const bf16x8*)(Wph);     w0[1] = *(const bf16x8*)(Wph + 8);
    w0[2] = *(const bf16x8*)(Wpl);     w0[3] = *(const bf16x8*)(Wpl + 8);

#pragma unroll 1
    for (int t = 0; t < 96; t += 2) {
        {   // even step t
            float f[16];
            feature16(f, a0v, s0v, t / 24);
            BAR();
            cvt_store16(f, Ahi, Alo, srow, h);
            store_pre16(w0, Bhi, Blo, srow, h);
            const int t1 = t + 1;                    // always < 96
            const int e1 = (t1 % 24) * 32;
            load16(Hp + e1, a1v); load16(Sp + e1, s1v);
            w1[0] = *(const bf16x8*)(Wph + t1 * 32);
            w1[1] = *(const bf16x8*)(Wph + t1 * 32 + 8);
            w1[2] = *(const bf16x8*)(Wpl + t1 * 32);
            w1[3] = *(const bf16x8*)(Wpl + t1 * 32 + 8);
            BAR();
            mfma_step(Ahi, Alo, Bhi, Blo, aoff, boff, acc);
        }
        {   // odd step t+1
            float f[16];
            feature16(f, a1v, s1v, (t + 1) / 24);
            BAR();
            cvt_store16(f, Ahi, Alo, srow, h);
            store_pre16(w1, Bhi, Blo, srow, h);
            if (t + 2 < 96) {
                const int t2 = t + 2;
                const int e2 = (t2 % 24) * 32;
                load16(Hp + e2, a0v); load16(Sp + e2, s0v);
                w0[0] = *(const bf16x8*)(Wph + t2 * 32);
                w0[1] = *(const bf16x8*)(Wph + t2 * 32 + 8);
                w0[2] = *(const bf16x8*)(Wpl + t2 * 32);
                w0[3] = *(const bf16x8*)(Wpl + t2 * 32 + 8);
            }
            BAR();
            mfma_step(Ahi, Alo, Bhi, Blo, aoff, boff, acc);
        }
    }

    const int b = m0 >> 9;
    float bv[4];
#pragma unroll
    for (int fn = 0; fn < 4; ++fn)
        bv[fn] = bias[n0 + wn * 64 + fn * 16 + l15];
    float sum4[4] = {0.f, 0.f, 0.f, 0.f}, max4[4] = {0.f, 0.f, 0.f, 0.f};
#pragma unroll
    for (int fm = 0; fm < 4; ++fm) {
        const int rbase = m0 + wm * 64 + fm * 16 + l4 * 4;
#pragma unroll
        for (int r = 0; r < 4; ++r) {
            const int g = rbase + r;
            const bool valid = ids[g] != 0;
#pragma unroll
            for (int fn = 0; fn < 4; ++fn) {
                float v = fmaxf(acc[fm][fn][r] + bv[fn], 0.f);
                v = valid ? v : 0.f;
                sum4[fn] += v;
                max4[fn] = fmaxf(max4[fn], v);
                if ((g & 511) == 0)   // row 0 of this batch -> "first" stat
                    stats[b * 2304 + n0 + wn * 64 + fn * 16 + l15] = v;
            }
        }
    }
#pragma unroll
    for (int fn = 0; fn < 4; ++fn) {
        float s = sum4[fn];
        s += __shfl_xor(s, 16); s += __shfl_xor(s, 32);
        float mx = max4[fn];
        mx = fmaxf(mx, __shfl_xor(mx, 16)); mx = fmaxf(mx, __shfl_xor(mx, 32));
        if (l4 == 0) {
            const int col = n0 + wn * 64 + fn * 16 + l15;
            atomicAdd(&stats[b * 2304 + 768 + col], s);
            atomicMax((int*)&stats[b * 2304 + 1536 + col], __float_as_int(mx));
        }
    }
}

// ---------------------------------------------------------------------------
// W_pre [3840][768] f32 -> folded WThi/WTlo [768][3072] bf16:
//   seg0 = W0+W2, seg1 = W1-W2, seg2 = W3 (ab), seg3 = W4 (d^2)
// ---------------------------------------------------------------------------
__global__ __launch_bounds__(256)
void combine_w(const float* __restrict__ src, __bf16* __restrict__ whi,
               __bf16* __restrict__ wlo) {
    __shared__ float tile[32][33];
    const int c0 = blockIdx.x * 32;   // n
    const int r0 = blockIdx.y * 32;   // k within 3072 (never crosses seg)
    const int seg = r0 / 768, e0 = r0 % 768;
    const int tx = threadIdx.x & 31, ty = threadIdx.x >> 5;
#pragma unroll
    for (int i = 0; i < 32; i += 8) {
        const int e = e0 + ty + i;
        float v;
        if (seg == 0)
            v = src[(size_t)e * 768 + c0 + tx] + src[(size_t)(1536 + e) * 768 + c0 + tx];
        else if (seg == 1)
            v = src[(size_t)(768 + e) * 768 + c0 + tx] - src[(size_t)(1536 + e) * 768 + c0 + tx];
        else if (seg == 2)
            v = src[(size_t)(2304 + e) * 768 + c0 + tx];
        else
            v = src[(size_t)(3072 + e) * 768 + c0 + tx];
        tile[ty + i][tx] = v;
    }
    __syncthreads();
    const int nr = threadIdx.x >> 3, kq = (threadIdx.x & 7) * 4;
#pragma unroll
    for (int j = 0; j < 4; ++j) {
        float v = tile[kq + j][nr];
        __bf16 hv = (__bf16)v;
        whi[(size_t)(c0 + nr) * 3072 + r0 + kq + j] = hv;
        wlo[(size_t)(c0 + nr) * 3072 + r0 + kq + j] = (__bf16)(v - (float)hv);
    }
}

// ---------------------------------------------------------------------------
// Row softmax, emitting pre-split hi/lo bf16
// ---------------------------------------------------------------------------
__global__ __launch_bounds__(256)
void softmax_rows(const float* __restrict__ att, __bf16* __restrict__ phi,
                  __bf16* __restrict__ plo) {
    const int wave = threadIdx.x >> 6;
    const int lane = threadIdx.x & 63;
    const size_t row = (size_t)blockIdx.x * 4 + wave;
    const float* x = att + row * N_;
    float v[8];
    float mx = -INFINITY;
#pragma unroll
    for (int i = 0; i < 8; ++i) { v[i] = x[lane + i * 64]; mx = fmaxf(mx, v[i]); }
#pragma unroll
    for (int off = 32; off; off >>= 1) mx = fmaxf(mx, __shfl_xor(mx, off));
    float s = 0.f;
#pragma unroll
    for (int i = 0; i < 8; ++i) { v[i] = __expf(v[i] - mx); s += v[i]; }
#pragma unroll
    for (int off = 32; off; off >>= 1) s += __shfl_xor(s, off);
    const float inv = 1.f / s;
#pragma unroll
    for (int i = 0; i < 8; ++i) {
        float val = v[i] * inv;
        __bf16 hv = (__bf16)val;
        phi[row * N_ + lane + i * 64] = hv;
        plo[row * N_ + lane + i * 64] = (__bf16)(val - (float)hv);
    }
}

// ---------------------------------------------------------------------------
// Column softmax (over m), transposed pre-split output P2t[b,n,m] hi/lo
// ---------------------------------------------------------------------------
__global__ __launch_bounds__(256)
void softmax_cols_t(const float* __restrict__ att, __bf16* __restrict__ dhi,
                    __bf16* __restrict__ dlo) {
    __shared__ float tile[512][17];
    __shared__ float red[16][16];
    __shared__ float invs[16];
    const int b = blockIdx.x, n0 = blockIdx.y * 16;
    const int tid = threadIdx.x;
    const int c = tid & 15, r = tid >> 4;
    const float* src = att + (size_t)b * M_ * N_ + n0;
#pragma unroll 4
    for (int i = 0; i < 32; ++i) {
        int m = r + i * 16;
        tile[m][c] = src[(size_t)m * N_ + c];
    }
    __syncthreads();
    float mx = -INFINITY;
    for (int m = r; m < 512; m += 16) mx = fmaxf(mx, tile[m][c]);
    red[r][c] = mx;
    __syncthreads();
    if (r == 0) {
        float m2 = red[0][c];
#pragma unroll
        for (int j = 1; j < 16; ++j) m2 = fmaxf(m2, red[j][c]);
        invs[c] = m2;
    }
    __syncthreads();
    const float cmx = invs[c];
    float s = 0.f;
    for (int m = r; m < 512; m += 16) {
        float e = __expf(tile[m][c] - cmx);
        tile[m][c] = e;
        s += e;
    }
    __syncthreads();
    red[r][c] = s;
    __syncthreads();
    if (r == 0) {
        float st = 0.f;
#pragma unroll
        for (int j = 0; j < 16; ++j) st += red[j][c];
        invs[c] = 1.f / st;
    }
    __syncthreads();
#pragma unroll 4
    for (int i = 0; i < 32; ++i) {
        int lin = tid + i * 256;
        int cc = lin >> 9;
        int m = lin & 511;
        float val = tile[m][cc] * invs[cc];
        __bf16 hv = (__bf16)val;
        const size_t o = ((size_t)b * N_ + n0 + cc) * M_ + m;
        dhi[o] = hv;
        dlo[o] = (__bf16)(val - (float)hv);
    }
}

// ---------------------------------------------------------------------------
// stats -> m_vs[b][11520] (submult of [first, sum/cnt, max] features)
// ---------------------------------------------------------------------------
__global__ __launch_bounds__(256)
void ffprep_kernel(const float* __restrict__ sc, const float* __restrict__ sr,
                   const int* __restrict__ cids, const int* __restrict__ rids,
                   float* __restrict__ mv) {
    __shared__ int redc[4], redr[4];
    const int b = blockIdx.x, tid = threadIdx.x;
    int cc = 0, cr = 0;
    for (int m = tid; m < 512; m += 256) {
        cc += (cids[b * 512 + m] != 0);
        cr += (rids[b * 512 + m] != 0);
    }
#pragma unroll
    for (int off = 32; off; off >>= 1) {
        cc += __shfl_xor(cc, off);
        cr += __shfl_xor(cr, off);
    }
    if ((tid & 63) == 0) { redc[tid >> 6] = cc; redr[tid >> 6] = cr; }
    __syncthreads();
    const float invc = 1.f / (float)(redc[0] + redc[1] + redc[2] + redc[3]);
    const float invr = 1.f / (float)(redr[0] + redr[1] + redr[2] + redr[3]);
    const float* scb = sc + b * 2304;
    const float* srb = sr + b * 2304;
    float* mvb = mv + (size_t)b * 11520;
    for (int i = tid; i < 2304; i += 256) {
        float a = scb[i], r = srb[i];
        if (i >= 768 && i < 1536) { a *= invc; r *= invr; }
        float d = a - r;
        mvb[i]        = a;
        mvb[2304 + i] = r;
        mvb[4608 + i] = d;
        mvb[6912 + i] = a * r;
        mvb[9216 + i] = d * d;
    }
}

// ---------------------------------------------------------------------------
// hacc[b][j] += partial dot over e-chunk; each W_ff1 element read once.
// ---------------------------------------------------------------------------
__global__ __launch_bounds__(256)
void ff1_kernel(const float* __restrict__ mv, const float* __restrict__ W1,
                float* __restrict__ hacc) {
    const int j = blockIdx.x * 256 + threadIdx.x;
    const int e0 = blockIdx.y * 720;
    float acc[32];
#pragma unroll
    for (int b = 0; b < 32; ++b) acc[b] = 0.f;
    for (int ec = 0; ec < 720; ec += 4) {
        const float w0 = W1[(size_t)(e0 + ec + 0) * 768 + j];
        const float w1 = W1[(size_t)(e0 + ec + 1) * 768 + j];
        const float w2 = W1[(size_t)(e0 + ec + 2) * 768 + j];
        const float w3 = W1[(size_t)(e0 + ec + 3) * 768 + j];
#pragma unroll
        for (int b = 0; b < 32; ++b) {
            const float* mp = mv + (size_t)b * 11520 + e0 + ec;
            float a = acc[b];
            a = fmaf(mp[0], w0, a);
            a = fmaf(mp[1], w1, a);
            a = fmaf(mp[2], w2, a);
            a = fmaf(mp[3], w3, a);
            acc[b] = a;
        }
    }
#pragma unroll
    for (int b = 0; b < 32; ++b) atomicAdd(&hacc[b * 768 + j], acc[b]);
}

// ---------------------------------------------------------------------------
// scores[b] = b2 + sum_j relu(hacc + b1)[j] * W2[j]
// ---------------------------------------------------------------------------
__global__ __launch_bounds__(256)
void score_kernel(const float* __restrict__ hacc, const float* __restrict__ b1,
                  const float* __restrict__ W2, const float* __restrict__ b2,
                  float* __restrict__ out) {
    const int b = blockIdx.x, tid = threadIdx.x;
    float acc = 0.f;
    for (int j = tid; j < 768; j += 256)
        acc += fmaxf(hacc[b * 768 + j] + b1[j], 0.f) * W2[j];
#pragma unroll
    for (int off = 32; off; off >>= 1) acc += __shfl_xor(acc, off);
    __shared__ float red[4];
    if ((tid & 63) == 0) red[tid >> 6] = acc;
    __syncthreads();
    if (tid == 0) out[b] = red[0] + red[1] + red[2] + red[3] + b2[0];
}

// ---------------------------------------------------------------------------
extern "C" void kernel_launch(void* const* d_in, const int* in_sizes, int n_in,
                              void* d_out, int out_size, void* d_ws, size_t ws_size,
                              hipStream_t stream) {
    const int*   c_ids = (const int*)d_in[0];
    const int*   r_ids = (const int*)d_in[1];
    const float* c_hs  = (const float*)d_in[2];
    const float* r_hs  = (const float*)d_in[3];
    const float* W_pre = (const float*)d_in[4];
    const float* b_pre = (const float*)d_in[5];
    const float* W_ff1 = (const float*)d_in[6];
    const float* b_ff1 = (const float*)d_in[7];
    const float* W_ff2 = (const float*)d_in[8];
    const float* b_ff2 = (const float*)d_in[9];
    float* out = (float*)d_out;
    float* ws  = (float*)d_ws;

    // Aliased layout (float offsets). Peak 37,748,736 floats = 144.0 MiB:
    //   att    [0,        8388608)   dead after softmaxes
    //   P1hi   [8388608, 12582912)   bf16 pair; dead after nn-chat
    //   P1lo   [12582912,16777216)
    //   P2thi  [16777216,20971520)   bf16 pair; dead after nn-rhat
    //   P2tlo  [20971520,25165824)
    //   chat   [25165824,37748736)   live through feat-c
    //   rhat   [0,       12582912)   over dead att+P1hi (written by nn-rhat)
    //   WThi/WTlo + sc/sr/hacc/mv inside dead-P1lo [12582912,16777216)
    float* att   = ws;
    __bf16* P1hi  = (__bf16*)(ws + 8388608);
    __bf16* P1lo  = (__bf16*)(ws + 12582912);
    __bf16* P2thi = (__bf16*)(ws + 16777216);
    __bf16* P2tlo = (__bf16*)(ws + 20971520);
    float* chat  = ws + 25165824;
    float* rhat  = ws;
    __bf16* WThi  = (__bf16*)(ws + 12582912);   // 768*3072 bf16 = 1,179,648 f
    __bf16* WTlo  = (__bf16*)(ws + 13762560);   // ends 14,942,208
    float* sc    = ws + 15532032;               // [B][3][768]
    float* sr    = sc + 73728;
    float* hacc  = sr + 73728;
    float* mv    = hacc + 24576;                // ends 16,072,704 < 16,777,216

    // 1. attention logits (masked, scaled)
    mfma_att<<<dim3(4, 4, 32), 256, 0, stream>>>(c_hs, r_hs, c_ids, r_ids, att);
    // 2. softmaxes -> pre-split bf16 pairs
    softmax_rows  <<<dim3(B_ * M_ / 4), 256, 0, stream>>>(att, P1hi, P1lo);
    softmax_cols_t<<<dim3(B_, 32), 256, 0, stream>>>(att, P2thi, P2tlo);
    // 3a. c_hat = P1 @ r_hs   (P1 dead after)
    mfma_nn<<<dim3(4, 6, 32), 256, 0, stream>>>(P1hi, P1lo, r_hs, chat);
    // P1lo region free: folded W transpose+split, zero stats
    combine_w<<<dim3(24, 96), 256, 0, stream>>>(W_pre, WThi, WTlo);
    hipMemsetAsync(sc, 0, 172032 * sizeof(float), stream);
    // 3b. r_hat = P2t @ c_hs  (P2t dead after)
    mfma_nn<<<dim3(4, 6, 32), 256, 0, stream>>>(P2thi, P2tlo, c_hs, rhat);
    // 4. fused feature GEMMs (separate dispatches -> per-side L3 residency)
    mfma_feat<<<dim3(128, 6), 256, 0, stream>>>(chat, c_hs, WThi, WTlo, b_pre,
                                                c_ids, sc);
    mfma_feat<<<dim3(128, 6), 256, 0, stream>>>(rhat, r_hs, WThi, WTlo, b_pre,
                                                r_ids, sr);
    // 5. FF head
    ffprep_kernel<<<dim3(32), 256, 0, stream>>>(sc, sr, c_ids, r_ids, mv);
    ff1_kernel<<<dim3(3, 16), 256, 0, stream>>>(mv, W_ff1, hacc);
    score_kernel<<<dim3(32), 256, 0, stream>>>(hacc, b_ff1, W_ff2, b_ff2, out);
}